// Round 1
// baseline (57.284 us; speedup 1.0000x reference)
//
#include <hip/hip_runtime.h>
#include <math.h>

// Bilaplacian of f(x) = tanh(x W1^T) W2^T reduces analytically to
//   out[b,o] = sum_h W2[o,h] * T4(z[b,h]) * S[h]^2
// where z[b,h] = sum_d x[b,d] W1[h,d], S[h] = sum_d W1[h,d]^2,
// and T4 = d^4 tanh / dz^4 = 8 t (1 - t^2)(2 - 3 t^2), t = tanh(z).
// (Each hidden unit sees x only through the scalar z_h; the linear map
// makes the D^2 direction-pair sum factor into S_h^2.)

#define BATCH 256
#define DIM   16
#define HID   128
#define NOUT  8

__global__ __launch_bounds__(HID) void bilap_kernel(
    const float* __restrict__ x,    // (BATCH, DIM)
    const float* __restrict__ W1,   // (HID, DIM)
    const float* __restrict__ W2,   // (NOUT, HID)
    float* __restrict__ out)        // (BATCH, NOUT)
{
    __shared__ float u[HID];

    const int b = blockIdx.x;   // batch row
    const int h = threadIdx.x;  // hidden unit

    // z_h = W1[h,:] . x[b,:],  S_h = ||W1[h,:]||^2
    float z = 0.f, S = 0.f;
    const float* w1 = W1 + h * DIM;
    const float* xr = x + b * DIM;
#pragma unroll
    for (int d = 0; d < DIM; ++d) {
        float w = w1[d];
        z += w * xr[d];       // xr broadcast across threads (L1-served)
        S += w * w;
    }

    float t   = tanhf(z);
    float s2  = 1.f - t * t;                  // sech^2
    float T4  = 8.f * t * s2 * (2.f - 3.f * t * t);
    u[h] = T4 * S * S;
    __syncthreads();

    // out[b,o] = sum_h W2[o,h] * u[h]
    // 8 groups of 16 lanes; groups are contiguous so they sit inside one wave.
    const int o    = h >> 4;   // 0..7
    const int lane = h & 15;   // 0..15
    float acc = 0.f;
#pragma unroll
    for (int k = 0; k < HID / 16; ++k) {
        int hh = lane + k * 16;
        acc += W2[o * HID + hh] * u[hh];
    }
#pragma unroll
    for (int s = 1; s < 16; s <<= 1)
        acc += __shfl_xor(acc, s, 64);

    if (lane == 0) out[b * NOUT + o] = acc;
}

extern "C" void kernel_launch(void* const* d_in, const int* in_sizes, int n_in,
                              void* d_out, int out_size, void* d_ws, size_t ws_size,
                              hipStream_t stream) {
    const float* x  = (const float*)d_in[0];
    const float* W1 = (const float*)d_in[1];
    const float* W2 = (const float*)d_in[2];
    float* out = (float*)d_out;

    bilap_kernel<<<BATCH, HID, 0, stream>>>(x, W1, W2, out);
}

// Round 2
// 56.859 us; speedup vs baseline: 1.0075x; 1.0075x over previous
//
#include <hip/hip_runtime.h>
#include <math.h>

// Bilaplacian of f(x) = tanh(x W1^T) W2^T reduces analytically to
//   out[b,o] = sum_h W2[o,h] * T4(z[b,h]) * S[h]^2
// where z[b,h] = sum_d x[b,d] W1[h,d], S[h] = sum_d W1[h,d]^2,
// and T4 = d^4 tanh / dz^4 = 8 t (1 - t^2)(2 - 3 t^2), t = tanh(z).
// (Each hidden unit sees x only through the scalar z_h; the linear map
// makes the D^2 direction-pair sum factor into S_h^2.)
//
// This round: 2 batch rows per 256-thread block (grid 128), fast tanh via
// __expf. Probe whether dur_us is kernel-bound or harness-floor-bound.

#define BATCH 256
#define DIM   16
#define HID   128
#define NOUT  8

__device__ __forceinline__ float fast_tanh(float z) {
    // tanh(z) = 1 - 2/(exp(2z)+1); monotone, saturates correctly at +-inf
    float e = __expf(2.0f * z);
    return 1.0f - 2.0f / (e + 1.0f);
}

__global__ __launch_bounds__(2 * HID) void bilap_kernel(
    const float* __restrict__ x,    // (BATCH, DIM)
    const float* __restrict__ W1,   // (HID, DIM)
    const float* __restrict__ W2,   // (NOUT, HID)
    float* __restrict__ out)        // (BATCH, NOUT)
{
    __shared__ float u[2][HID];

    const int r = threadIdx.x >> 7;          // row within block (0/1)
    const int h = threadIdx.x & (HID - 1);   // hidden unit
    const int b = (blockIdx.x << 1) + r;     // batch row

    // z_h = W1[h,:] . x[b,:],  S_h = ||W1[h,:]||^2
    float z = 0.f, S = 0.f;
    const float* w1 = W1 + h * DIM;
    const float* xr = x + b * DIM;
#pragma unroll
    for (int d = 0; d < DIM; ++d) {
        float w = w1[d];
        z += w * xr[d];       // xr broadcast across the 128 threads (L1)
        S += w * w;
    }

    float t  = fast_tanh(z);
    float s2 = 1.f - t * t;                   // sech^2
    float T4 = 8.f * t * s2 * (2.f - 3.f * t * t);
    u[r][h] = T4 * S * S;
    __syncthreads();

    // out[b,o] = sum_h W2[o,h] * u[r][h]
    // 8 groups of 16 lanes; each 16-lane group sits inside one wave.
    const int o    = h >> 4;   // 0..7
    const int lane = h & 15;   // 0..15
    float acc = 0.f;
#pragma unroll
    for (int k = 0; k < HID / 16; ++k) {
        int hh = lane + k * 16;
        acc += W2[o * HID + hh] * u[r][hh];
    }
#pragma unroll
    for (int s = 1; s < 16; s <<= 1)
        acc += __shfl_xor(acc, s, 64);

    if (lane == 0) out[b * NOUT + o] = acc;
}

extern "C" void kernel_launch(void* const* d_in, const int* in_sizes, int n_in,
                              void* d_out, int out_size, void* d_ws, size_t ws_size,
                              hipStream_t stream) {
    const float* x  = (const float*)d_in[0];
    const float* W1 = (const float*)d_in[1];
    const float* W2 = (const float*)d_in[2];
    float* out = (float*)d_out;

    bilap_kernel<<<BATCH / 2, 2 * HID, 0, stream>>>(x, W1, W2, out);
}